// Round 1
// baseline (156.286 us; speedup 1.0000x reference)
//
#include <hip/hip_runtime.h>
#include <math.h>

constexpr int BD = 1024;
constexpr float EPS = 1e-3f;

__device__ __forceinline__ float wave_allsum(float v) {
#pragma unroll
    for (int m = 1; m < 64; m <<= 1) v += __shfl_xor(v, m, 64);
    return v;
}

__device__ __forceinline__ float dot16(const float4* a, const float4* b) {
    float s = 0.f;
#pragma unroll
    for (int e = 0; e < 4; ++e) {
        s = fmaf(a[e].x, b[e].x, s);
        s = fmaf(a[e].y, b[e].y, s);
        s = fmaf(a[e].z, b[e].z, s);
        s = fmaf(a[e].w, b[e].w, s);
    }
    return s;
}

__device__ __forceinline__ float bcast_lane(float v, int j) {
    return __uint_as_float(__builtin_amdgcn_readlane(__float_as_uint(v), j));
}

__global__ __launch_bounds__(256, 2) void dcn_fused(
    const float* __restrict__ x,        // [16384][1024]
    const float* __restrict__ cross_w,  // [3][1024]
    const float* __restrict__ cross_b,  // [3][1024]
    const float* __restrict__ w1,       // [1024][64]
    const float* __restrict__ b1,
    const float* __restrict__ g1, const float* __restrict__ be1,
    const float* __restrict__ m1, const float* __restrict__ v1,
    const float* __restrict__ w2,       // [64][48]
    const float* __restrict__ b2,
    const float* __restrict__ g2, const float* __restrict__ be2,
    const float* __restrict__ m2, const float* __restrict__ v2,
    const float* __restrict__ w3,       // [48][24]
    const float* __restrict__ b3,
    const float* __restrict__ g3, const float* __restrict__ be3,
    const float* __restrict__ m3, const float* __restrict__ v3,
    const float* __restrict__ w_out,    // [1048]
    const float* __restrict__ b_out,    // [1]
    float* __restrict__ out)            // [16384]
{
    const int lane = threadIdx.x & 63;
    const int wid  = __builtin_amdgcn_readfirstlane((int)(threadIdx.x >> 6));
    const int row0 = blockIdx.x * 32 + wid * 8;   // 8 rows per wave
    const int fo   = lane * 4;                    // frag: k = e*256 + lane*4

    // ---------------- Phase A: cross-network scalars ----------------
    float4 cwf0[4], cwf1[4], cwf2[4], wof[4];
#pragma unroll
    for (int e = 0; e < 4; ++e) {
        cwf0[e] = *(const float4*)(cross_w + 0 * BD + e * 256 + fo);
        cwf1[e] = *(const float4*)(cross_w + 1 * BD + e * 256 + fo);
        cwf2[e] = *(const float4*)(cross_w + 2 * BD + e * 256 + fo);
        wof[e]  = *(const float4*)(w_out + e * 256 + fo);
    }

    // constants: q2 = cb0.cw1 ; q3 = (cb0+cb1).cw2 ; C = (cb0+cb1+cb2).wo
    float4 cbs[4];
#pragma unroll
    for (int e = 0; e < 4; ++e) cbs[e] = *(const float4*)(cross_b + 0 * BD + e * 256 + fo);
    const float q2 = wave_allsum(dot16(cbs, cwf1));
#pragma unroll
    for (int e = 0; e < 4; ++e) {
        float4 t = *(const float4*)(cross_b + 1 * BD + e * 256 + fo);
        cbs[e].x += t.x; cbs[e].y += t.y; cbs[e].z += t.z; cbs[e].w += t.w;
    }
    const float q3 = wave_allsum(dot16(cbs, cwf2));
#pragma unroll
    for (int e = 0; e < 4; ++e) {
        float4 t = *(const float4*)(cross_b + 2 * BD + e * 256 + fo);
        cbs[e].x += t.x; cbs[e].y += t.y; cbs[e].z += t.z; cbs[e].w += t.w;
    }
    const float Cc = wave_allsum(dot16(cbs, wof));

    float lc[8];
#pragma unroll
    for (int r = 0; r < 8; ++r) {
        const float* xr = x + (size_t)(row0 + r) * BD;
        float4 xf[4];
#pragma unroll
        for (int e = 0; e < 4; ++e) xf[e] = *(const float4*)(xr + e * 256 + fo);
        const float p1 = wave_allsum(dot16(xf, cwf0));
        const float p2 = wave_allsum(dot16(xf, cwf1));
        const float p3 = wave_allsum(dot16(xf, cwf2));
        const float d0 = wave_allsum(dot16(xf, wof));
        const float s1 = p1;
        const float s2 = fmaf(1.f + s1, p2, q2);
        const float s3 = fmaf(1.f + s1 + s2, p3, q3);
        const float alpha = 1.f + s1 + s2 + s3;
        lc[r] = fmaf(alpha, d0, Cc);
    }

    // ---------------- Phase B: layer-1 GEMM (j = lane) ----------------
    float acc[8] = {0.f, 0.f, 0.f, 0.f, 0.f, 0.f, 0.f, 0.f};
    for (int k0 = 0; k0 < BD; k0 += 16) {
        float wv[16];
#pragma unroll
        for (int e = 0; e < 16; ++e) wv[e] = w1[(k0 + e) * 64 + lane];
#pragma unroll
        for (int r = 0; r < 8; ++r) {
            const float4* xr = (const float4*)(x + (size_t)(row0 + r) * BD + k0);
#pragma unroll
            for (int q = 0; q < 4; ++q) {
                const float4 xv = xr[q];
                acc[r] = fmaf(xv.x, wv[4 * q + 0], acc[r]);
                acc[r] = fmaf(xv.y, wv[4 * q + 1], acc[r]);
                acc[r] = fmaf(xv.z, wv[4 * q + 2], acc[r]);
                acc[r] = fmaf(xv.w, wv[4 * q + 3], acc[r]);
            }
        }
    }

    // bias + relu + BN1 (feature j = lane)
    {
        const float b1l = b1[lane], g1l = g1[lane], be1l = be1[lane], m1l = m1[lane];
        const float iv1 = rsqrtf(v1[lane] + EPS);
#pragma unroll
        for (int r = 0; r < 8; ++r) {
            const float y = fmaxf(acc[r] + b1l, 0.f);
            acc[r] = fmaf(g1l * (y - m1l), iv1, be1l);
        }
    }

    // ---------------- Phase C: layers 2/3 in registers ----------------
    // layer 2: feature j2 = lane (valid < 48)
    const int j2 = lane < 48 ? lane : 0;
    const float b2l = b2[j2], g2l = g2[j2], be2l = be2[j2], m2l = m2[j2];
    const float iv2 = rsqrtf(v2[j2] + EPS);
    float w2c[64];
#pragma unroll
    for (int j = 0; j < 64; ++j) w2c[j] = w2[j * 48 + j2];

    float h2a[8];
#pragma unroll
    for (int r = 0; r < 8; ++r) h2a[r] = b2l;
#pragma unroll
    for (int j = 0; j < 64; ++j) {
#pragma unroll
        for (int r = 0; r < 8; ++r)
            h2a[r] = fmaf(bcast_lane(acc[r], j), w2c[j], h2a[r]);
    }
#pragma unroll
    for (int r = 0; r < 8; ++r) {
        const float t = tanhf(h2a[r]);
        h2a[r] = fmaf(g2l * (t - m2l), iv2, be2l);
    }

    // layer 3: feature j3 = lane (valid < 24)
    const int j3 = lane < 24 ? lane : 0;
    const float b3l = b3[j3], g3l = g3[j3], be3l = be3[j3], m3l = m3[j3];
    const float iv3 = rsqrtf(v3[j3] + EPS);
    float w3c[48];
#pragma unroll
    for (int j = 0; j < 48; ++j) w3c[j] = w3[j * 24 + j3];

    float h3a[8];
#pragma unroll
    for (int r = 0; r < 8; ++r) h3a[r] = b3l;
#pragma unroll
    for (int j = 0; j < 48; ++j) {
#pragma unroll
        for (int r = 0; r < 8; ++r)
            h3a[r] = fmaf(bcast_lane(h2a[r], j), w3c[j], h3a[r]);
    }
#pragma unroll
    for (int r = 0; r < 8; ++r) {
        const float t = tanhf(h3a[r]);
        h3a[r] = fmaf(g3l * (t - m3l), iv3, be3l);
    }

    // tower output + final logit + sigmoid
    const float wo2l = (lane < 24) ? w_out[1024 + lane] : 0.f;
    const float bo = b_out[0];
#pragma unroll
    for (int r = 0; r < 8; ++r) {
        const float tow = wave_allsum(h3a[r] * wo2l);
        const float z = lc[r] + tow + bo;
        const float o = 1.f / (1.f + expf(-z));
        if (lane == r) out[row0 + r] = o;
    }
}

extern "C" void kernel_launch(void* const* d_in, const int* in_sizes, int n_in,
                              void* d_out, int out_size, void* d_ws, size_t ws_size,
                              hipStream_t stream) {
    const float* x       = (const float*)d_in[0];
    const float* cross_w = (const float*)d_in[1];
    const float* cross_b = (const float*)d_in[2];
    const float* w1      = (const float*)d_in[3];
    const float* b1      = (const float*)d_in[4];
    const float* g1      = (const float*)d_in[5];
    const float* be1     = (const float*)d_in[6];
    const float* m1      = (const float*)d_in[7];
    const float* v1      = (const float*)d_in[8];
    const float* w2      = (const float*)d_in[9];
    const float* b2      = (const float*)d_in[10];
    const float* g2      = (const float*)d_in[11];
    const float* be2     = (const float*)d_in[12];
    const float* m2      = (const float*)d_in[13];
    const float* v2      = (const float*)d_in[14];
    const float* w3      = (const float*)d_in[15];
    const float* b3      = (const float*)d_in[16];
    const float* g3      = (const float*)d_in[17];
    const float* be3     = (const float*)d_in[18];
    const float* m3      = (const float*)d_in[19];
    const float* v3      = (const float*)d_in[20];
    const float* w_out   = (const float*)d_in[21];
    const float* b_out   = (const float*)d_in[22];
    float* out = (float*)d_out;

    dcn_fused<<<512, 256, 0, stream>>>(x, cross_w, cross_b,
                                       w1, b1, g1, be1, m1, v1,
                                       w2, b2, g2, be2, m2, v2,
                                       w3, b3, g3, be3, m3, v3,
                                       w_out, b_out, out);
}

// Round 2
// 41.484 us; speedup vs baseline: 3.7674x; 3.7674x over previous
//
#include <hip/hip_runtime.h>
#include <hip/hip_bf16.h>
#include <math.h>

typedef __attribute__((ext_vector_type(8))) short bf16x8;
typedef __attribute__((ext_vector_type(4))) float f32x4;

constexpr int BD = 1024;
constexpr float EPS = 1e-3f;
// Wb fragment store: [32 ksteps][6 tiles][64 lanes][8 bf16]
constexpr int WB_BYTES = 32 * 6 * 64 * 8 * 2;  // 196608

__device__ __forceinline__ float wave_allsum(float v) {
#pragma unroll
    for (int m = 1; m < 64; m <<= 1) v += __shfl_xor(v, m, 64);
    return v;
}
__device__ __forceinline__ unsigned short f2bf(float f) {
    __hip_bfloat16 h = __float2bfloat16(f);   // RNE
    unsigned short u; __builtin_memcpy(&u, &h, 2);
    return u;
}
__device__ __forceinline__ float bf2f(unsigned short u) {
    return __uint_as_float(((unsigned)u) << 16);
}
__device__ __forceinline__ float bcast_lane(float v, int j) {
    return __uint_as_float(__builtin_amdgcn_readlane(__float_as_uint(v), j));
}

// ---------------- prep: build bf16 B-fragments + cross constants ----------------
__global__ void dcn_prep(const float* __restrict__ w1,
                         const float* __restrict__ cross_w,
                         const float* __restrict__ cross_b,
                         const float* __restrict__ w_out,
                         unsigned short* __restrict__ wb,
                         float* __restrict__ consts) {
    if (blockIdx.x == 48) {
        if (threadIdx.x < 64) {
            const int l = threadIdx.x;
            float q2 = 0.f, q3 = 0.f, Cc = 0.f;
            for (int j = 0; j < 16; ++j) {
                const int k = l * 16 + j;
                const float c0 = cross_b[k], c1 = cross_b[BD + k], c2 = cross_b[2 * BD + k];
                q2 += c0 * cross_w[BD + k];
                q3 += (c0 + c1) * cross_w[2 * BD + k];
                Cc += (c0 + c1 + c2) * w_out[k];
            }
            q2 = wave_allsum(q2); q3 = wave_allsum(q3); Cc = wave_allsum(Cc);
            if (l == 0) { consts[0] = q2; consts[1] = q3; consts[2] = Cc; }
        }
        return;
    }
    const int idx = blockIdx.x * 256 + threadIdx.x;   // [0, 12288)
    const int g = idx / 384;          // k-step 0..31
    const int rem = idx - g * 384;
    const int t = rem >> 6;           // tile 0..5
    const int l = rem & 63;           // lane
    const int c = l & 15;             // col within tile
    const int k0 = g * 32 + (l >> 4) * 8;
    unsigned short o[8] __attribute__((aligned(16)));
#pragma unroll
    for (int j = 0; j < 8; ++j) {
        const int k = k0 + j;
        float v;
        if (t < 4) v = w1[k * 64 + t * 16 + c];
        else v = (c < 3) ? cross_w[c * BD + k] : ((c == 3) ? w_out[k] : 0.f);
        const unsigned short h = f2bf(v);
        o[j] = (t == 5) ? f2bf(v - bf2f(h)) : h;
    }
    *(uint4*)(wb + (size_t)idx * 8) = *(const uint4*)o;
}

// ---------------- main fused kernel ----------------
__global__ __launch_bounds__(256, 4) void dcn_main(
    const float* __restrict__ x,
    const unsigned short* __restrict__ wb,
    const float* __restrict__ consts,
    const float* __restrict__ b1, const float* __restrict__ g1,
    const float* __restrict__ be1, const float* __restrict__ m1, const float* __restrict__ v1,
    const float* __restrict__ w2, const float* __restrict__ b2,
    const float* __restrict__ g2, const float* __restrict__ be2,
    const float* __restrict__ m2, const float* __restrict__ v2,
    const float* __restrict__ w3, const float* __restrict__ b3,
    const float* __restrict__ g3, const float* __restrict__ be3,
    const float* __restrict__ m3, const float* __restrict__ v3,
    const float* __restrict__ w_out, const float* __restrict__ b_out,
    float* __restrict__ out)
{
    __shared__ char sb[20480] __attribute__((aligned(16)));

    const int tid = threadIdx.x;
    const int lane = tid & 63;
    const int w = tid >> 6;                 // wave 0..3 (k-step within chunk)
    const int row0 = blockIdx.x * 16;

    // --- staging (reg -> LDS) addresses: chunk = 16 rows x 128 k f32, XOR-swizzled rows
    const int r_st = tid >> 4;                       // row 0..15
    const int kst = (tid & 15) * 8;                  // k within chunk
    const unsigned swz_st = ((unsigned)(r_st & 7)) << 4;
    const int wb0 = kst * 4;                         // byte within row
    const int st_off0 = r_st * 512 + ((unsigned)wb0 ^ swz_st);
    const int st_off1 = r_st * 512 + ((unsigned)(wb0 + 16) ^ swz_st);
    const float* xsrc = x + (size_t)(row0 + r_st) * BD + kst;

    // --- A-fragment ds_read addresses (within buffer)
    const int ar = lane & 15;                        // row
    const int aq = lane >> 4;                        // k quarter
    const unsigned swz_a = ((unsigned)(ar & 7)) << 4;
    const int ab = w * 128 + aq * 32;                // byte k-offset of this wave's k-step
    const int aoff0 = ar * 512 + (((unsigned)ab) ^ swz_a);
    const int aoff1 = ar * 512 + (((unsigned)(ab + 16)) ^ swz_a);

    f32x4 acc0 = {0.f,0.f,0.f,0.f}, acc1 = acc0, acc2 = acc0, acc3 = acc0, acc4 = acc0;

    // prologue: stage chunk 0 into buffer 0
    {
        float4 s0 = *(const float4*)(xsrc);
        float4 s1 = *(const float4*)(xsrc + 4);
        *(float4*)&sb[st_off0] = s0;
        *(float4*)&sb[st_off1] = s1;
    }
    __syncthreads();

    for (int c = 0; c < 8; ++c) {
        const int cb = (c & 1) * 8192;
        float4 n0, n1;
        if (c < 7) {                                   // T14: issue next-chunk loads early
            const float* nsrc = xsrc + (c + 1) * 128;
            n0 = *(const float4*)(nsrc);
            n1 = *(const float4*)(nsrc + 4);
        }
        // B fragments (global, L2-hot): k-step g = c*4 + w
        const bf16x8* bp = (const bf16x8*)wb + ((size_t)(c * 4 + w) * 6) * 64 + lane;
        const bf16x8 B0 = bp[0];
        const bf16x8 B1 = bp[64];
        const bf16x8 B2 = bp[128];
        const bf16x8 B3 = bp[192];
        const bf16x8 B4 = bp[256];   // cross hi
        const bf16x8 B5 = bp[320];   // cross lo

        // A fragment from LDS
        const float4 a0 = *(const float4*)&sb[cb + aoff0];
        const float4 a1 = *(const float4*)&sb[cb + aoff1];

        bf16x8 xh, xl;
#define CVT(F, I) { const unsigned short h_ = f2bf(F); xh[I] = (short)h_; \
                    xl[I] = (short)f2bf((F) - bf2f(h_)); }
        CVT(a0.x, 0) CVT(a0.y, 1) CVT(a0.z, 2) CVT(a0.w, 3)
        CVT(a1.x, 4) CVT(a1.y, 5) CVT(a1.z, 6) CVT(a1.w, 7)
#undef CVT

        acc0 = __builtin_amdgcn_mfma_f32_16x16x32_bf16(xh, B0, acc0, 0, 0, 0);
        acc1 = __builtin_amdgcn_mfma_f32_16x16x32_bf16(xh, B1, acc1, 0, 0, 0);
        acc2 = __builtin_amdgcn_mfma_f32_16x16x32_bf16(xh, B2, acc2, 0, 0, 0);
        acc3 = __builtin_amdgcn_mfma_f32_16x16x32_bf16(xh, B3, acc3, 0, 0, 0);
        acc4 = __builtin_amdgcn_mfma_f32_16x16x32_bf16(xh, B4, acc4, 0, 0, 0);
        acc4 = __builtin_amdgcn_mfma_f32_16x16x32_bf16(xl, B4, acc4, 0, 0, 0);
        acc4 = __builtin_amdgcn_mfma_f32_16x16x32_bf16(xh, B5, acc4, 0, 0, 0);

        if (c < 7) {
            __syncthreads();                           // everyone done reading buf[(c+1)&1]
            const int nb = ((c + 1) & 1) * 8192;
            *(float4*)&sb[nb + st_off0] = n0;          // compiler inserts vmcnt wait
            *(float4*)&sb[nb + st_off1] = n1;
            __syncthreads();                           // staged before next compute
        }
    }
    __syncthreads();   // staging region dead; reuse LDS for split-k reduce

    // --- split-k reduce: plane t at t*4096 + (w*64 + lane)*16
    *(f32x4*)&sb[0 * 4096 + (w * 64 + lane) * 16] = acc0;
    *(f32x4*)&sb[1 * 4096 + (w * 64 + lane) * 16] = acc1;
    *(f32x4*)&sb[2 * 4096 + (w * 64 + lane) * 16] = acc2;
    *(f32x4*)&sb[3 * 4096 + (w * 64 + lane) * 16] = acc3;
    *(f32x4*)&sb[4 * 4096 + (w * 64 + lane) * 16] = acc4;
    __syncthreads();

    // wave 0: sum partials, apply bias+relu+BN1, write h1 [16][64] f32 at 0, cross p's at 4096
    if (w == 0) {
#pragma unroll
        for (int t = 0; t < 5; ++t) {
            f32x4 s = *(const f32x4*)&sb[t * 4096 + (0 * 64 + lane) * 16];
            s += *(const f32x4*)&sb[t * 4096 + (1 * 64 + lane) * 16];
            s += *(const f32x4*)&sb[t * 4096 + (2 * 64 + lane) * 16];
            s += *(const f32x4*)&sb[t * 4096 + (3 * 64 + lane) * 16];
            if (t < 4) {
                const int col = t * 16 + ar;
                const float b1c = b1[col], g1c = g1[col], be1c = be1[col], m1c = m1[col];
                const float iv1c = rsqrtf(v1[col] + EPS);
#pragma unroll
                for (int q = 0; q < 4; ++q) {
                    const float y = fmaxf(s[q] + b1c, 0.f);
                    const float h = fmaf(g1c * (y - m1c), iv1c, be1c);
                    *(float*)&sb[((aq * 4 + q) * 64 + col) * 4] = h;
                }
            } else {
                if (ar < 4) {
#pragma unroll
                    for (int q = 0; q < 4; ++q)
                        *(float*)&sb[4096 + ((aq * 4 + q) * 4 + ar) * 4] = s[q];
                }
            }
        }
    }
    __syncthreads();

    // --- phase C: tower + cross logit; wave w owns rows w*4 .. w*4+3; lane = col
    float h1r[4];
#pragma unroll
    for (int q = 0; q < 4; ++q)
        h1r[q] = *(const float*)&sb[((w * 4 + q) * 64 + lane) * 4];

    const float q2c = consts[0], q3c = consts[1], Ccc = consts[2];
    float lc[4];
#pragma unroll
    for (int q = 0; q < 4; ++q) {
        const f32x4 cr = *(const f32x4*)&sb[4096 + (w * 4 + q) * 16];
        const float p1 = cr[0], p2 = cr[1], p3 = cr[2], d0 = cr[3];
        const float s1 = p1;
        const float s2 = fmaf(1.f + s1, p2, q2c);
        const float s3 = fmaf(1.f + s1 + s2, p3, q3c);
        const float alpha = 1.f + s1 + s2 + s3;
        lc[q] = fmaf(alpha, d0, Ccc);
    }

    // layer 2 (64 -> 48), col = lane (<48)
    const int c2 = lane < 48 ? lane : 0;
    const float b2l = b2[c2], g2l = g2[c2], be2l = be2[c2], m2l = m2[c2];
    const float iv2 = rsqrtf(v2[c2] + EPS);
    float h2a[4] = {b2l, b2l, b2l, b2l};
#pragma unroll
    for (int j = 0; j < 64; ++j) {
        const float wj = w2[j * 48 + c2];
#pragma unroll
        for (int q = 0; q < 4; ++q)
            h2a[q] = fmaf(bcast_lane(h1r[q], j), wj, h2a[q]);
    }
#pragma unroll
    for (int q = 0; q < 4; ++q) {
        const float t = tanhf(h2a[q]);
        h2a[q] = fmaf(g2l * (t - m2l), iv2, be2l);
    }

    // layer 3 (48 -> 24), col = lane (<24)
    const int c3 = lane < 24 ? lane : 0;
    const float b3l = b3[c3], g3l = g3[c3], be3l = be3[c3], m3l = m3[c3];
    const float iv3 = rsqrtf(v3[c3] + EPS);
    float h3a[4] = {b3l, b3l, b3l, b3l};
#pragma unroll
    for (int j = 0; j < 48; ++j) {
        const float wj = w3[j * 24 + c3];
#pragma unroll
        for (int q = 0; q < 4; ++q)
            h3a[q] = fmaf(bcast_lane(h2a[q], j), wj, h3a[q]);
    }
#pragma unroll
    for (int q = 0; q < 4; ++q) {
        const float t = tanhf(h3a[q]);
        h3a[q] = fmaf(g3l * (t - m3l), iv3, be3l);
    }

    const float wo2l = (lane < 24) ? w_out[1024 + lane] : 0.f;
    const float bo = b_out[0];
#pragma unroll
    for (int q = 0; q < 4; ++q) {
        const float tow = wave_allsum(h3a[q] * wo2l);
        const float z = lc[q] + tow + bo;
        const float o = 1.f / (1.f + expf(-z));
        if (lane == q) out[row0 + w * 4 + q] = o;
    }
}

extern "C" void kernel_launch(void* const* d_in, const int* in_sizes, int n_in,
                              void* d_out, int out_size, void* d_ws, size_t ws_size,
                              hipStream_t stream) {
    const float* x       = (const float*)d_in[0];
    const float* cross_w = (const float*)d_in[1];
    const float* cross_b = (const float*)d_in[2];
    const float* w1      = (const float*)d_in[3];
    const float* b1      = (const float*)d_in[4];
    const float* g1      = (const float*)d_in[5];
    const float* be1     = (const float*)d_in[6];
    const float* m1      = (const float*)d_in[7];
    const float* v1      = (const float*)d_in[8];
    const float* w2      = (const float*)d_in[9];
    const float* b2      = (const float*)d_in[10];
    const float* g2      = (const float*)d_in[11];
    const float* be2     = (const float*)d_in[12];
    const float* m2      = (const float*)d_in[13];
    const float* v2      = (const float*)d_in[14];
    const float* w3      = (const float*)d_in[15];
    const float* b3      = (const float*)d_in[16];
    const float* g3      = (const float*)d_in[17];
    const float* be3     = (const float*)d_in[18];
    const float* m3      = (const float*)d_in[19];
    const float* v3      = (const float*)d_in[20];
    const float* w_out   = (const float*)d_in[21];
    const float* b_out   = (const float*)d_in[22];
    float* out = (float*)d_out;

    unsigned short* wbuf = (unsigned short*)d_ws;
    float* consts = (float*)((char*)d_ws + WB_BYTES);

    dcn_prep<<<49, 256, 0, stream>>>(w1, cross_w, cross_b, w_out, wbuf, consts);
    dcn_main<<<1024, 256, 0, stream>>>(x, wbuf, consts,
                                       b1, g1, be1, m1, v1,
                                       w2, b2, g2, be2, m2, v2,
                                       w3, b3, g3, be3, m3, v3,
                                       w_out, b_out, out);
}

// Round 3
// 35.995 us; speedup vs baseline: 4.3418x; 1.1525x over previous
//
#include <hip/hip_runtime.h>
#include <hip/hip_bf16.h>
#include <math.h>

typedef __attribute__((ext_vector_type(8))) short bf16x8;
typedef __attribute__((ext_vector_type(4))) float f32x4;

constexpr int BD = 1024;
constexpr float EPS = 1e-3f;
// Wb fragment store: [32 ksteps][5 tiles][64 lanes][8 bf16]
constexpr int WB_BYTES = 32 * 5 * 64 * 8 * 2;  // 163840

__device__ __forceinline__ float wave_allsum(float v) {
#pragma unroll
    for (int m = 1; m < 64; m <<= 1) v += __shfl_xor(v, m, 64);
    return v;
}
__device__ __forceinline__ unsigned short f2bf(float f) {
    __hip_bfloat16 h = __float2bfloat16(f);   // RNE
    unsigned short u; __builtin_memcpy(&u, &h, 2);
    return u;
}
__device__ __forceinline__ float bf2f(unsigned short u) {
    return __uint_as_float(((unsigned)u) << 16);
}
__device__ __forceinline__ float bcast_lane(float v, int j) {
    return __uint_as_float(__builtin_amdgcn_readlane(__float_as_uint(v), j));
}

// ---------------- prep: build bf16 B-fragments + cross constants ----------------
// tiles 0..3: w1 cols t*16..t*16+15 (bf16 hi)
// tile 4: cols 0-3 = [cw0,cw1,cw2,w_out] hi ; cols 4-7 = same, lo ; cols 8-15 = 0
__global__ void dcn_prep(const float* __restrict__ w1,
                         const float* __restrict__ cross_w,
                         const float* __restrict__ cross_b,
                         const float* __restrict__ w_out,
                         unsigned short* __restrict__ wb,
                         float* __restrict__ consts) {
    if (blockIdx.x == 40) {
        if (threadIdx.x < 64) {
            const int l = threadIdx.x;
            float q2 = 0.f, q3 = 0.f, Cc = 0.f;
            for (int j = 0; j < 16; ++j) {
                const int k = l * 16 + j;
                const float c0 = cross_b[k], c1 = cross_b[BD + k], c2 = cross_b[2 * BD + k];
                q2 += c0 * cross_w[BD + k];
                q3 += (c0 + c1) * cross_w[2 * BD + k];
                Cc += (c0 + c1 + c2) * w_out[k];
            }
            q2 = wave_allsum(q2); q3 = wave_allsum(q3); Cc = wave_allsum(Cc);
            if (l == 0) { consts[0] = q2; consts[1] = q3; consts[2] = Cc; }
        }
        return;
    }
    const int idx = blockIdx.x * 256 + threadIdx.x;   // [0, 10240)
    const int g = idx / 320;          // k-step 0..31
    const int rem = idx - g * 320;
    const int t = rem >> 6;           // tile 0..4
    const int l = rem & 63;           // lane
    const int c = l & 15;             // col within tile
    const int k0 = g * 32 + (l >> 4) * 8;
    unsigned short o[8] __attribute__((aligned(16)));
#pragma unroll
    for (int j = 0; j < 8; ++j) {
        const int k = k0 + j;
        unsigned short r;
        if (t < 4) {
            r = f2bf(w1[k * 64 + t * 16 + c]);
        } else if (c < 8) {
            const int vsel = c & 3;
            const float v = (vsel < 3) ? cross_w[vsel * BD + k] : w_out[k];
            const unsigned short h = f2bf(v);
            r = (c < 4) ? h : f2bf(v - bf2f(h));
        } else {
            r = 0;
        }
        o[j] = r;
    }
    *(uint4*)(wb + (size_t)idx * 8) = *(const uint4*)o;
}

// ---------------- main fused kernel ----------------
__global__ __launch_bounds__(256, 4) void dcn_main(
    const float* __restrict__ x,
    const unsigned short* __restrict__ wb,
    const float* __restrict__ consts,
    const float* __restrict__ b1, const float* __restrict__ g1,
    const float* __restrict__ be1, const float* __restrict__ m1, const float* __restrict__ v1,
    const float* __restrict__ w2, const float* __restrict__ b2,
    const float* __restrict__ g2, const float* __restrict__ be2,
    const float* __restrict__ m2, const float* __restrict__ v2,
    const float* __restrict__ w3, const float* __restrict__ b3,
    const float* __restrict__ g3, const float* __restrict__ be3,
    const float* __restrict__ m3, const float* __restrict__ v3,
    const float* __restrict__ w_out, const float* __restrict__ b_out,
    float* __restrict__ out)
{
    __shared__ char sb[20480] __attribute__((aligned(16)));

    const int tid = threadIdx.x;
    const int lane = tid & 63;
    const int w = tid >> 6;                 // wave 0..3 = k-quarter
    const int row0 = blockIdx.x * 16;
    const int ar = lane & 15;               // A row within tile
    const int aq = lane >> 4;               // A k-subblock (8 floats)

    // per-lane A source: row (row0+ar), k = w*256 + aq*8 + s*32
    const float* xbase = x + (size_t)(row0 + ar) * BD + w * 256 + aq * 8;

    // B fragments for this wave's k-steps g = w*8 + s
    const bf16x8* bbase = (const bf16x8*)wb + (size_t)(w * 8 * 5) * 64 + lane;

    // ---- prologue: A loads 4-deep, B step 0 ----
    float4 a0[4], a1[4];
#pragma unroll
    for (int s = 0; s < 4; ++s) {
        a0[s] = *(const float4*)(xbase + s * 32);
        a1[s] = *(const float4*)(xbase + s * 32 + 4);
    }
    bf16x8 Bc[5];
#pragma unroll
    for (int t = 0; t < 5; ++t) Bc[t] = bbase[t * 64];

    f32x4 acc0 = {0.f,0.f,0.f,0.f}, acc1 = acc0, acc2 = acc0, acc3 = acc0, acc4 = acc0;

#pragma unroll
    for (int s = 0; s < 8; ++s) {
        bf16x8 Bn[5];
        if (s < 7) {
#pragma unroll
            for (int t = 0; t < 5; ++t) Bn[t] = bbase[((s + 1) * 5 + t) * 64];
        }
        const float4 va0 = a0[s & 3];
        const float4 va1 = a1[s & 3];
        if (s < 4) {   // reload slot for step s+4
            a0[s & 3] = *(const float4*)(xbase + (s + 4) * 32);
            a1[s & 3] = *(const float4*)(xbase + (s + 4) * 32 + 4);
        }
        bf16x8 xh, xl;
#define CVT(F, I) { const unsigned short h_ = f2bf(F); xh[I] = (short)h_; \
                    xl[I] = (short)f2bf((F) - bf2f(h_)); }
        CVT(va0.x, 0) CVT(va0.y, 1) CVT(va0.z, 2) CVT(va0.w, 3)
        CVT(va1.x, 4) CVT(va1.y, 5) CVT(va1.z, 6) CVT(va1.w, 7)
#undef CVT
        acc0 = __builtin_amdgcn_mfma_f32_16x16x32_bf16(xh, Bc[0], acc0, 0, 0, 0);
        acc1 = __builtin_amdgcn_mfma_f32_16x16x32_bf16(xh, Bc[1], acc1, 0, 0, 0);
        acc2 = __builtin_amdgcn_mfma_f32_16x16x32_bf16(xh, Bc[2], acc2, 0, 0, 0);
        acc3 = __builtin_amdgcn_mfma_f32_16x16x32_bf16(xh, Bc[3], acc3, 0, 0, 0);
        acc4 = __builtin_amdgcn_mfma_f32_16x16x32_bf16(xh, Bc[4], acc4, 0, 0, 0);
        acc4 = __builtin_amdgcn_mfma_f32_16x16x32_bf16(xl, Bc[4], acc4, 0, 0, 0);
#pragma unroll
        for (int t = 0; t < 5; ++t) Bc[t] = Bn[t];
    }

    // ---- split-k reduce via LDS ----
    *(f32x4*)&sb[0 * 4096 + (w * 64 + lane) * 16] = acc0;
    *(f32x4*)&sb[1 * 4096 + (w * 64 + lane) * 16] = acc1;
    *(f32x4*)&sb[2 * 4096 + (w * 64 + lane) * 16] = acc2;
    *(f32x4*)&sb[3 * 4096 + (w * 64 + lane) * 16] = acc3;
    *(f32x4*)&sb[4 * 4096 + (w * 64 + lane) * 16] = acc4;
    __syncthreads();

    if (w == 0) {
#pragma unroll
        for (int t = 0; t < 5; ++t) {
            f32x4 s = *(const f32x4*)&sb[t * 4096 + (0 * 64 + lane) * 16];
            s += *(const f32x4*)&sb[t * 4096 + (1 * 64 + lane) * 16];
            s += *(const f32x4*)&sb[t * 4096 + (2 * 64 + lane) * 16];
            s += *(const f32x4*)&sb[t * 4096 + (3 * 64 + lane) * 16];
            if (t < 4) {
                const int col = t * 16 + ar;
                const float b1c = b1[col], g1c = g1[col], be1c = be1[col], m1c = m1[col];
                const float iv1c = rsqrtf(v1[col] + EPS);
#pragma unroll
                for (int q = 0; q < 4; ++q) {
                    const float y = fmaxf(s[q] + b1c, 0.f);
                    const float h = fmaf(g1c * (y - m1c), iv1c, be1c);
                    *(float*)&sb[((aq * 4 + q) * 64 + col) * 4] = h;
                }
            } else {
                // p_i = sum(col i) + sum(col i+4)  (hi + lo parts)
                f32x4 xs;
#pragma unroll
                for (int q = 0; q < 4; ++q) xs[q] = __shfl_xor(s[q], 4, 64);
                if (ar < 4) {
#pragma unroll
                    for (int q = 0; q < 4; ++q)
                        *(float*)&sb[4096 + ((aq * 4 + q) * 4 + ar) * 4] = s[q] + xs[q];
                }
            }
        }
    }
    __syncthreads();

    // ---- phase C: tower + cross logit; wave w owns rows w*4..w*4+3, lane = col ----
    float h1r[4];
#pragma unroll
    for (int q = 0; q < 4; ++q)
        h1r[q] = *(const float*)&sb[((w * 4 + q) * 64 + lane) * 4];

    const float q2c = consts[0], q3c = consts[1], Ccc = consts[2];
    float lc[4];
#pragma unroll
    for (int q = 0; q < 4; ++q) {
        const f32x4 cr = *(const f32x4*)&sb[4096 + (w * 4 + q) * 16];
        const float p1 = cr[0], p2 = cr[1], p3 = cr[2], d0 = cr[3];
        const float s1 = p1;
        const float s2 = fmaf(1.f + s1, p2, q2c);
        const float s3 = fmaf(1.f + s1 + s2, p3, q3c);
        const float alpha = 1.f + s1 + s2 + s3;
        lc[q] = fmaf(alpha, d0, Ccc);
    }

    // layer 2 (64 -> 48), col = lane (<48)
    const int c2 = lane < 48 ? lane : 0;
    const float b2l = b2[c2], g2l = g2[c2], be2l = be2[c2], m2l = m2[c2];
    const float iv2 = rsqrtf(v2[c2] + EPS);
    float h2a[4] = {b2l, b2l, b2l, b2l};
#pragma unroll
    for (int j = 0; j < 64; ++j) {
        const float wj = w2[j * 48 + c2];
#pragma unroll
        for (int q = 0; q < 4; ++q)
            h2a[q] = fmaf(bcast_lane(h1r[q], j), wj, h2a[q]);
    }
#pragma unroll
    for (int q = 0; q < 4; ++q) {
        const float t = tanhf(h2a[q]);
        h2a[q] = fmaf(g2l * (t - m2l), iv2, be2l);
    }

    // layer 3 (48 -> 24), col = lane (<24)
    const int c3 = lane < 24 ? lane : 0;
    const float b3l = b3[c3], g3l = g3[c3], be3l = be3[c3], m3l = m3[c3];
    const float iv3 = rsqrtf(v3[c3] + EPS);
    float h3a[4] = {b3l, b3l, b3l, b3l};
#pragma unroll
    for (int j = 0; j < 48; ++j) {
        const float wj = w3[j * 24 + c3];
#pragma unroll
        for (int q = 0; q < 4; ++q)
            h3a[q] = fmaf(bcast_lane(h2a[q], j), wj, h3a[q]);
    }
#pragma unroll
    for (int q = 0; q < 4; ++q) {
        const float t = tanhf(h3a[q]);
        h3a[q] = fmaf(g3l * (t - m3l), iv3, be3l);
    }

    const float wo2l = (lane < 24) ? w_out[1024 + lane] : 0.f;
    const float bo = b_out[0];
#pragma unroll
    for (int q = 0; q < 4; ++q) {
        const float tow = wave_allsum(h3a[q] * wo2l);
        const float z = lc[q] + tow + bo;
        const float o = 1.f / (1.f + expf(-z));
        if (lane == q) out[row0 + w * 4 + q] = o;
    }
}

extern "C" void kernel_launch(void* const* d_in, const int* in_sizes, int n_in,
                              void* d_out, int out_size, void* d_ws, size_t ws_size,
                              hipStream_t stream) {
    const float* x       = (const float*)d_in[0];
    const float* cross_w = (const float*)d_in[1];
    const float* cross_b = (const float*)d_in[2];
    const float* w1      = (const float*)d_in[3];
    const float* b1      = (const float*)d_in[4];
    const float* g1      = (const float*)d_in[5];
    const float* be1     = (const float*)d_in[6];
    const float* m1      = (const float*)d_in[7];
    const float* v1      = (const float*)d_in[8];
    const float* w2      = (const float*)d_in[9];
    const float* b2      = (const float*)d_in[10];
    const float* g2      = (const float*)d_in[11];
    const float* be2     = (const float*)d_in[12];
    const float* m2      = (const float*)d_in[13];
    const float* v2      = (const float*)d_in[14];
    const float* w3      = (const float*)d_in[15];
    const float* b3      = (const float*)d_in[16];
    const float* g3      = (const float*)d_in[17];
    const float* be3     = (const float*)d_in[18];
    const float* m3      = (const float*)d_in[19];
    const float* v3      = (const float*)d_in[20];
    const float* w_out   = (const float*)d_in[21];
    const float* b_out   = (const float*)d_in[22];
    float* out = (float*)d_out;

    unsigned short* wbuf = (unsigned short*)d_ws;
    float* consts = (float*)((char*)d_ws + WB_BYTES);

    dcn_prep<<<41, 256, 0, stream>>>(w1, cross_w, cross_b, w_out, wbuf, consts);
    dcn_main<<<1024, 256, 0, stream>>>(x, wbuf, consts,
                                       b1, g1, be1, m1, v1,
                                       w2, b2, g2, be2, m2, v2,
                                       w3, b3, g3, be3, m3, v3,
                                       w_out, b_out, out);
}

// Round 4
// 25.978 us; speedup vs baseline: 6.0161x; 1.3856x over previous
//
#include <hip/hip_runtime.h>
#include <hip/hip_bf16.h>
#include <math.h>

typedef __attribute__((ext_vector_type(8))) short bf16x8;
typedef __attribute__((ext_vector_type(4))) float f32x4;

constexpr int BD = 1024;
constexpr float EPS = 1e-3f;
// d_ws layout
constexpr int WB_MAIN = 32 * 5 * 64 * 8 * 2;    // 163840  [32 ksteps][5 tiles][64 lanes][8 bf16]
constexpr int WB2_OFF = WB_MAIN;                 // w2 frags: 6*64*8*2 = 6144
constexpr int WB3_OFF = WB2_OFF + 6144;          // w3 frags: 4*64*8*2 = 4096
constexpr int CST_OFF = WB3_OFF + 4096;          // 3 floats

__device__ __forceinline__ float wave_allsum(float v) {
#pragma unroll
    for (int m = 1; m < 64; m <<= 1) v += __shfl_xor(v, m, 64);
    return v;
}
__device__ __forceinline__ unsigned short f2bf(float f) {
    __hip_bfloat16 h = __float2bfloat16(f);   // RNE
    unsigned short u; __builtin_memcpy(&u, &h, 2);
    return u;
}
__device__ __forceinline__ float bf2f(unsigned short u) {
    return __uint_as_float(((unsigned)u) << 16);
}
__device__ __forceinline__ float tanh_fast(float x) {
    const float xc = fminf(fmaxf(x, -15.f), 15.f);
    const float e = __expf(2.f * xc);
    return (e - 1.f) * __builtin_amdgcn_rcpf(e + 1.f);
}
__device__ __forceinline__ float sigmoid_fast(float z) {
    return __builtin_amdgcn_rcpf(1.f + __expf(-z));
}

// ---------------- prep: bf16 B-fragments (w1+cross, w2, w3) + cross constants ----------------
__global__ void dcn_prep(const float* __restrict__ w1,
                         const float* __restrict__ cross_w,
                         const float* __restrict__ cross_b,
                         const float* __restrict__ w_out,
                         const float* __restrict__ w2,
                         const float* __restrict__ w3,
                         unsigned short* __restrict__ ws) {
    const int bx = blockIdx.x;
    if (bx == 40) {                       // cross constants
        if (threadIdx.x < 64) {
            const int l = threadIdx.x;
            float q2 = 0.f, q3 = 0.f, Cc = 0.f;
            for (int j = 0; j < 16; ++j) {
                const int k = l * 16 + j;
                const float c0 = cross_b[k], c1 = cross_b[BD + k], c2 = cross_b[2 * BD + k];
                q2 += c0 * cross_w[BD + k];
                q3 += (c0 + c1) * cross_w[2 * BD + k];
                Cc += (c0 + c1 + c2) * w_out[k];
            }
            q2 = wave_allsum(q2); q3 = wave_allsum(q3); Cc = wave_allsum(Cc);
            float* consts = (float*)((char*)ws + CST_OFF);
            if (l == 0) { consts[0] = q2; consts[1] = q3; consts[2] = Cc; }
        }
        return;
    }
    if (bx < 40) {                        // main-GEMM fragments
        const int idx = bx * 256 + threadIdx.x;   // [0, 10240)
        const int g = idx / 320;          // k-step 0..31
        const int rem = idx - g * 320;
        const int t = rem >> 6;           // tile 0..4
        const int l = rem & 63;
        const int c = l & 15;
        const int k0 = g * 32 + (l >> 4) * 8;
        unsigned short o[8] __attribute__((aligned(16)));
#pragma unroll
        for (int j = 0; j < 8; ++j) {
            const int k = k0 + j;
            unsigned short r;
            if (t < 4) {
                r = f2bf(w1[k * 64 + t * 16 + c]);
            } else if (c < 8) {
                const int vsel = c & 3;
                const float v = (vsel < 3) ? cross_w[vsel * BD + k] : w_out[k];
                const unsigned short h = f2bf(v);
                r = (c < 4) ? h : f2bf(v - bf2f(h));
            } else {
                r = 0;
            }
            o[j] = r;
        }
        *(uint4*)(ws + (size_t)idx * 8) = *(const uint4*)o;
        return;
    }
    // bx in 41..43 : tower fragments
    const int slot = (bx - 41) * 256 + threadIdx.x;   // [0, 768)
    if (slot < 384) {                     // w2: f = K*3+T, frag [64][8]
        const int f = slot >> 6, l = slot & 63;
        const int K = f / 3, T = f % 3;
        const int kb = K * 32 + (l >> 4) * 8;
        const int col = T * 16 + (l & 15);
        unsigned short o[8] __attribute__((aligned(16)));
#pragma unroll
        for (int j = 0; j < 8; ++j) o[j] = f2bf(w2[(kb + j) * 48 + col]);
        unsigned short* wb2 = (unsigned short*)((char*)ws + WB2_OFF);
        *(uint4*)(wb2 + (size_t)slot * 8) = *(const uint4*)o;
    } else if (slot < 640) {              // w3: f = K*2+T (zero-padded k>=48, col>=24)
        const int s2 = slot - 384;
        const int f = s2 >> 6, l = s2 & 63;
        const int K = f >> 1, T = f & 1;
        const int kb = K * 32 + (l >> 4) * 8;
        const int col = T * 16 + (l & 15);
        unsigned short o[8] __attribute__((aligned(16)));
#pragma unroll
        for (int j = 0; j < 8; ++j) {
            const int k = kb + j;
            o[j] = (k < 48 && col < 24) ? f2bf(w3[k * 24 + col]) : (unsigned short)0;
        }
        unsigned short* wb3 = (unsigned short*)((char*)ws + WB3_OFF);
        *(uint4*)(wb3 + (size_t)s2 * 8) = *(const uint4*)o;
    }
}

// ---------------- main: 1 wave = 16 rows end-to-end, no barriers ----------------
__global__ __launch_bounds__(64, 1) void dcn_main(
    const float* __restrict__ x,
    const unsigned short* __restrict__ wbm,
    const unsigned short* __restrict__ w2f,
    const unsigned short* __restrict__ w3f,
    const float* __restrict__ consts,
    const float* __restrict__ b1, const float* __restrict__ g1,
    const float* __restrict__ be1, const float* __restrict__ m1, const float* __restrict__ v1,
    const float* __restrict__ b2, const float* __restrict__ g2,
    const float* __restrict__ be2, const float* __restrict__ m2, const float* __restrict__ v2,
    const float* __restrict__ b3, const float* __restrict__ g3,
    const float* __restrict__ be3, const float* __restrict__ m3, const float* __restrict__ v3,
    const float* __restrict__ w_out, const float* __restrict__ b_out,
    float* __restrict__ out)
{
    // per-block (1 wave) LDS: h1 [16 rows x 272B], h2 [16 x 272B], lc [16 x 16B]
    __shared__ char sb[8960] __attribute__((aligned(16)));
    constexpr int H1 = 0, H2 = 4352, LC = 8704;

    const int l = threadIdx.x;            // lane 0..63
    const int ar = l & 15;                // fragment row
    const int ag = l >> 4;                // k sub-block
    const int gr0 = blockIdx.x * 16;

    const float* xbase = x + (size_t)(gr0 + ar) * BD + ag * 8;
    const bf16x8* bb = (const bf16x8*)wbm + l;

    // ---- uniform / per-lane preloads (issue early) ----
    const float q2c = consts[0], q3c = consts[1], Ccc = consts[2];
    const float bo = b_out[0];
    const float wo0 = w_out[1024 + ar];
    const float wo1 = (ar < 8) ? w_out[1040 + ar] : 0.f;
    float b1p[4], g1p[4], be1p[4], m1p[4], iv1p[4];
#pragma unroll
    for (int t = 0; t < 4; ++t) {
        const int c = t * 16 + ar;
        b1p[t] = b1[c]; g1p[t] = g1[c]; be1p[t] = be1[c]; m1p[t] = m1[c];
        iv1p[t] = rsqrtf(v1[c] + EPS);
    }

    // ---- main K loop: A 6-deep, B 4-deep prefetch ----
    float4 A0[6], A1[6];
#pragma unroll
    for (int s = 0; s < 6; ++s) {
        A0[s] = *(const float4*)(xbase + s * 32);
        A1[s] = *(const float4*)(xbase + s * 32 + 4);
    }
    bf16x8 Bf[4][5];
#pragma unroll
    for (int s = 0; s < 4; ++s)
#pragma unroll
        for (int t = 0; t < 5; ++t) Bf[s][t] = bb[(s * 5 + t) * 64];

    f32x4 acc0 = {0.f,0.f,0.f,0.f}, acc1 = acc0, acc2 = acc0, acc3 = acc0, acc4 = acc0;

#pragma unroll
    for (int s = 0; s < 32; ++s) {
        const float4 va0 = A0[s % 6];
        const float4 va1 = A1[s % 6];
        if (s + 6 < 32) {
            A0[s % 6] = *(const float4*)(xbase + (s + 6) * 32);
            A1[s % 6] = *(const float4*)(xbase + (s + 6) * 32 + 4);
        }
        const bf16x8 B0 = Bf[s & 3][0], B1 = Bf[s & 3][1], B2 = Bf[s & 3][2],
                     B3 = Bf[s & 3][3], B4 = Bf[s & 3][4];
        if (s + 4 < 32) {
#pragma unroll
            for (int t = 0; t < 5; ++t) Bf[s & 3][t] = bb[((s + 4) * 5 + t) * 64];
        }
        bf16x8 xh, xl;
#define CVT(F, I) { const unsigned short h_ = f2bf(F); xh[I] = (short)h_; \
                    xl[I] = (short)f2bf((F) - bf2f(h_)); }
        CVT(va0.x, 0) CVT(va0.y, 1) CVT(va0.z, 2) CVT(va0.w, 3)
        CVT(va1.x, 4) CVT(va1.y, 5) CVT(va1.z, 6) CVT(va1.w, 7)
#undef CVT
        acc0 = __builtin_amdgcn_mfma_f32_16x16x32_bf16(xh, B0, acc0, 0, 0, 0);
        acc1 = __builtin_amdgcn_mfma_f32_16x16x32_bf16(xh, B1, acc1, 0, 0, 0);
        acc2 = __builtin_amdgcn_mfma_f32_16x16x32_bf16(xh, B2, acc2, 0, 0, 0);
        acc3 = __builtin_amdgcn_mfma_f32_16x16x32_bf16(xh, B3, acc3, 0, 0, 0);
        acc4 = __builtin_amdgcn_mfma_f32_16x16x32_bf16(xh, B4, acc4, 0, 0, 0);
        acc4 = __builtin_amdgcn_mfma_f32_16x16x32_bf16(xl, B4, acc4, 0, 0, 0);
    }

    // ---- epilogue (intra-wave only) ----
    // issue tower-weight loads first so latency hides under BN1/LDS work
    const bf16x8* w2b = (const bf16x8*)w2f + l;
    bf16x8 W2[6];
#pragma unroll
    for (int f = 0; f < 6; ++f) W2[f] = w2b[f * 64];
    const bf16x8* w3b = (const bf16x8*)w3f + l;
    bf16x8 W3[4];
#pragma unroll
    for (int f = 0; f < 4; ++f) W3[f] = w3b[f * 64];
    float b2p[3], g2p[3], be2p[3], m2p[3], iv2p[3];
#pragma unroll
    for (int t = 0; t < 3; ++t) {
        const int c = t * 16 + ar;
        b2p[t] = b2[c]; g2p[t] = g2[c]; be2p[t] = be2[c]; m2p[t] = m2[c];
        iv2p[t] = rsqrtf(v2[c] + EPS);
    }
    float b3p[2], g3p[2], be3p[2], m3p[2], iv3p[2];
#pragma unroll
    for (int t = 0; t < 2; ++t) {
        const int c = t == 0 ? ar : (16 + ar < 24 ? 16 + ar : 23);
        b3p[t] = b3[c]; g3p[t] = g3[c]; be3p[t] = be3[c]; m3p[t] = m3[c];
        iv3p[t] = rsqrtf(v3[c] + EPS);
    }

    // cross scalars: fold lo cols (4..7) into hi (0..3), park per-row in LDS
    {
        f32x4 p4 = acc4;
#pragma unroll
        for (int q = 0; q < 4; ++q) p4[q] += __shfl_xor(acc4[q], 4, 64);
        if (ar < 4) {
#pragma unroll
            for (int q = 0; q < 4; ++q)
                *(float*)&sb[LC + ((ag * 4 + q) * 4 + ar) * 4] = p4[q];
        }
    }

    // BN1 + relu, write h1 tile [16 rows][64 cols] f32, row stride 272B
    {
        const f32x4 av[4] = {acc0, acc1, acc2, acc3};
#pragma unroll
        for (int t = 0; t < 4; ++t) {
            const int c = t * 16 + ar;
#pragma unroll
            for (int q = 0; q < 4; ++q) {
                const float y = fmaxf(av[t][q] + b1p[t], 0.f);
                const float h = fmaf(g1p[t] * (y - m1p[t]), iv1p[t], be1p[t]);
                *(float*)&sb[H1 + (ag * 4 + q) * 272 + c * 4] = h;
            }
        }
    }
    // zero-fill h2 cols 48..63 (finite garbage guard for layer-3 A)
    {
        const f32x4 z4 = {0.f, 0.f, 0.f, 0.f};
        *(f32x4*)&sb[H2 + ar * 272 + 192 + ag * 16] = z4;
    }

    // layer 2: h1 -> (tanh,BN) -> h2   via MFMA
    bf16x8 a2[2];
#pragma unroll
    for (int K = 0; K < 2; ++K) {
        const float4 f0 = *(const float4*)&sb[H1 + ar * 272 + (K * 32 + ag * 8) * 4];
        const float4 f1 = *(const float4*)&sb[H1 + ar * 272 + (K * 32 + ag * 8) * 4 + 16];
        const float v[8] = {f0.x, f0.y, f0.z, f0.w, f1.x, f1.y, f1.z, f1.w};
#pragma unroll
        for (int i = 0; i < 8; ++i) a2[K][i] = (short)f2bf(v[i]);
    }
    f32x4 c2t[3] = {{0.f,0.f,0.f,0.f},{0.f,0.f,0.f,0.f},{0.f,0.f,0.f,0.f}};
#pragma unroll
    for (int K = 0; K < 2; ++K) {
        c2t[0] = __builtin_amdgcn_mfma_f32_16x16x32_bf16(a2[K], W2[K * 3 + 0], c2t[0], 0, 0, 0);
        c2t[1] = __builtin_amdgcn_mfma_f32_16x16x32_bf16(a2[K], W2[K * 3 + 1], c2t[1], 0, 0, 0);
        c2t[2] = __builtin_amdgcn_mfma_f32_16x16x32_bf16(a2[K], W2[K * 3 + 2], c2t[2], 0, 0, 0);
    }
#pragma unroll
    for (int t = 0; t < 3; ++t) {
        const int c = t * 16 + ar;
#pragma unroll
        for (int q = 0; q < 4; ++q) {
            const float th = tanh_fast(c2t[t][q] + b2p[t]);
            const float h = fmaf(g2p[t] * (th - m2p[t]), iv2p[t], be2p[t]);
            *(float*)&sb[H2 + (ag * 4 + q) * 272 + c * 4] = h;
        }
    }

    // layer 3: h2 -> (tanh,BN) -> h3   via MFMA (w3 zero-padded handles k/col tails)
    bf16x8 a3[2];
#pragma unroll
    for (int K = 0; K < 2; ++K) {
        const float4 f0 = *(const float4*)&sb[H2 + ar * 272 + (K * 32 + ag * 8) * 4];
        const float4 f1 = *(const float4*)&sb[H2 + ar * 272 + (K * 32 + ag * 8) * 4 + 16];
        const float v[8] = {f0.x, f0.y, f0.z, f0.w, f1.x, f1.y, f1.z, f1.w};
#pragma unroll
        for (int i = 0; i < 8; ++i) a3[K][i] = (short)f2bf(v[i]);
    }
    f32x4 c3t[2] = {{0.f,0.f,0.f,0.f},{0.f,0.f,0.f,0.f}};
#pragma unroll
    for (int K = 0; K < 2; ++K) {
        c3t[0] = __builtin_amdgcn_mfma_f32_16x16x32_bf16(a3[K], W3[K * 2 + 0], c3t[0], 0, 0, 0);
        c3t[1] = __builtin_amdgcn_mfma_f32_16x16x32_bf16(a3[K], W3[K * 2 + 1], c3t[1], 0, 0, 0);
    }
    // tanh+BN3, weighted col-sum (wo1=0 masks cols>=24), 16-lane tree reduce
    float contrib[4];
#pragma unroll
    for (int q = 0; q < 4; ++q) {
        const float t0 = tanh_fast(c3t[0][q] + b3p[0]);
        const float h0 = fmaf(g3p[0] * (t0 - m3p[0]), iv3p[0], be3p[0]);
        const float t1 = tanh_fast(c3t[1][q] + b3p[1]);
        const float h1v = fmaf(g3p[1] * (t1 - m3p[1]), iv3p[1], be3p[1]);
        contrib[q] = h0 * wo0 + h1v * wo1;
    }
#pragma unroll
    for (int m = 1; m < 16; m <<= 1) {
#pragma unroll
        for (int q = 0; q < 4; ++q) contrib[q] += __shfl_xor(contrib[q], m, 64);
    }

    // cross recurrence + sigmoid + store (lane ar==q writes row ag*4+q)
#pragma unroll
    for (int q = 0; q < 4; ++q) {
        const f32x4 pr = *(const f32x4*)&sb[LC + (ag * 4 + q) * 16];
        const float p1 = pr[0], p2 = pr[1], p3 = pr[2], d0 = pr[3];
        const float s1 = p1;
        const float s2 = fmaf(1.f + s1, p2, q2c);
        const float s3 = fmaf(1.f + s1 + s2, p3, q3c);
        const float alpha = 1.f + s1 + s2 + s3;
        const float z = fmaf(alpha, d0, Ccc) + contrib[q] + bo;
        const float o = sigmoid_fast(z);
        if (ar == q) out[gr0 + ag * 4 + q] = o;
    }
}

extern "C" void kernel_launch(void* const* d_in, const int* in_sizes, int n_in,
                              void* d_out, int out_size, void* d_ws, size_t ws_size,
                              hipStream_t stream) {
    const float* x       = (const float*)d_in[0];
    const float* cross_w = (const float*)d_in[1];
    const float* cross_b = (const float*)d_in[2];
    const float* w1      = (const float*)d_in[3];
    const float* b1      = (const float*)d_in[4];
    const float* g1      = (const float*)d_in[5];
    const float* be1     = (const float*)d_in[6];
    const float* m1      = (const float*)d_in[7];
    const float* v1      = (const float*)d_in[8];
    const float* w2      = (const float*)d_in[9];
    const float* b2      = (const float*)d_in[10];
    const float* g2      = (const float*)d_in[11];
    const float* be2     = (const float*)d_in[12];
    const float* m2      = (const float*)d_in[13];
    const float* v2      = (const float*)d_in[14];
    const float* w3      = (const float*)d_in[15];
    const float* b3      = (const float*)d_in[16];
    const float* g3      = (const float*)d_in[17];
    const float* be3     = (const float*)d_in[18];
    const float* m3      = (const float*)d_in[19];
    const float* v3      = (const float*)d_in[20];
    const float* w_out   = (const float*)d_in[21];
    const float* b_out   = (const float*)d_in[22];
    float* out = (float*)d_out;

    unsigned short* ws = (unsigned short*)d_ws;
    const unsigned short* w2f = (const unsigned short*)((char*)d_ws + WB2_OFF);
    const unsigned short* w3f = (const unsigned short*)((char*)d_ws + WB3_OFF);
    const float* consts = (const float*)((char*)d_ws + CST_OFF);

    dcn_prep<<<44, 256, 0, stream>>>(w1, cross_w, cross_b, w_out, w2, w3, ws);
    dcn_main<<<1024, 64, 0, stream>>>(x, ws, w2f, w3f, consts,
                                      b1, g1, be1, m1, v1,
                                      b2, g2, be2, m2, v2,
                                      b3, g3, be3, m3, v3,
                                      w_out, b_out, out);
}